// Round 1
// baseline (509.841 us; speedup 1.0000x reference)
//
#include <hip/hip_runtime.h>
#include <hip/hip_bf16.h>
#include <stdint.h>

// bf16 MFMA fragment types (per guide §3: short-based ext vectors)
typedef short bhalf8 __attribute__((ext_vector_type(8)));
typedef float facc4 __attribute__((ext_vector_type(4)));

static __device__ __forceinline__ short f2bf(float f) {
  uint32_t u = __builtin_bit_cast(uint32_t, f);
  u = (u + 0x7FFFu + ((u >> 16) & 1u)) >> 16;  // RNE
  return (short)(uint16_t)u;
}

// ---------------------------------------------------------------------------
// prep: sample conv weights w = loc + L@eps (L = tril(-1) + softplus(diag)*I)
// into bf16 layout wt[a=kh*3+kw][o][i] (i contiguous -> K-contig A frags),
// and bias = bias_loc + eps_b * softplus(bias_ro).
// ---------------------------------------------------------------------------
__global__ void prep_kernel(const float* __restrict__ wloc,
                            const float* __restrict__ wL,
                            const float* __restrict__ eps_w,
                            const float* __restrict__ bloc,
                            const float* __restrict__ bro,
                            const float* __restrict__ eps_b,
                            short* __restrict__ wt,
                            float* __restrict__ bias) {
  int t = blockIdx.x * 256 + threadIdx.x;  // t = o*64 + i, 0..4095
  int o = t >> 6, i = t & 63;
  const float* Lp = wL + (size_t)t * 81;
  const float* ep = eps_w + (size_t)t * 9;
  const float* lp = wloc + (size_t)t * 9;
  float e[9];
#pragma unroll
  for (int b = 0; b < 9; ++b) e[b] = ep[b];
#pragma unroll
  for (int a = 0; a < 9; ++a) {
    float s = lp[a];
    for (int b = 0; b < a; ++b) s += Lp[a * 9 + b] * e[b];
    float d = Lp[a * 9 + a];
    float sp = (d > 20.f) ? d : log1pf(expf(d));  // softplus, stable
    s += sp * e[a];
    wt[(a * 64 + o) * 64 + i] = f2bf(s);
  }
  if (t < 64) {
    float d = bro[t];
    float sp = (d > 20.f) ? d : log1pf(expf(d));
    bias[t] = bloc[t] + eps_b[t] * sp;
  }
}

// ---------------------------------------------------------------------------
// conv: 3x3 SAME conv as 9 shifted GEMMs with mfma_f32_16x16x32_bf16.
// Block: 64 o x (8 rows x 64 cols) px, 8 waves (one out-row each).
// LDS x-tile [10 rows][66 cols][32 i] bf16, staged twice (i in 2 chunks),
// in-LDS NCHW->(px,i) transpose, 16B-chunk XOR swizzle g^=((c>>1)&3).
// A-frags (weights, 73.7 KB total) read straight from global (L1/L2-hot).
// ---------------------------------------------------------------------------
#define LDSH (10 * 66 * 32)  // shorts = 42240 B

__global__ __launch_bounds__(512, 2) void conv_kernel(
    const float* __restrict__ x, const short* __restrict__ wt,
    const float* __restrict__ bias, float* __restrict__ out) {
  __shared__ short lds[LDSH];
  int b = blockIdx.x;
  int n = b / 112;          // 28 h-tiles * 4 w-tiles
  int rem = b % 112;
  int h0 = (rem >> 2) * 8;  // 0..216
  int w0 = (rem & 3) * 64;  // 0,64,128,192 (last tile: cols 192..223 valid)
  int t = threadIdx.x;
  int lane = t & 63, wv = t >> 6;
  int l15 = lane & 15, l4 = lane >> 4;

  facc4 acc[4][4];
#pragma unroll
  for (int om = 0; om < 4; ++om)
#pragma unroll
    for (int p = 0; p < 4; ++p) {
      facc4 z = {0.f, 0.f, 0.f, 0.f};
      acc[om][p] = z;
    }

  for (int ic = 0; ic < 2; ++ic) {
    // ---- stage [10][66][32i]: 2640 16B chunks; id = (r*4+g)*66 + c ----
    for (int k = 0; k < 6; ++k) {
      int id = t + k * 512;
      if (id < 2640) {
        int cc = id % 66;
        int rg = id / 66;
        int g = rg & 3, r = rg >> 2;
        int h_in = h0 - 1 + r, w_in = w0 - 1 + cc;
        bhalf8 v = {0, 0, 0, 0, 0, 0, 0, 0};
        if (h_in >= 0 && h_in < 224 && w_in >= 0 && w_in < 224) {
          const float* xp =
              x + ((size_t)((n * 64 + ic * 32 + g * 8) * 224 + h_in)) * 224 +
              w_in;
#pragma unroll
          for (int j = 0; j < 8; ++j) v[j] = f2bf(xp[(size_t)j * 50176]);
        }
        *(bhalf8*)(lds + (r * 66 + cc) * 32 + ((g ^ ((cc >> 1) & 3)) << 3)) = v;
      }
    }
    __syncthreads();
    // ---- compute: 9 shifted K=32 GEMM steps ----
#pragma unroll
    for (int kh = 0; kh < 3; ++kh) {
      int r = wv + kh;  // input tile row for this wave's out-row
#pragma unroll
      for (int kw = 0; kw < 3; ++kw) {
        const short* wbase =
            wt + ((kh * 3 + kw) * 64) * 64 + ic * 32 + (l4 << 3);
        bhalf8 a[4], bb[4];
#pragma unroll
        for (int om = 0; om < 4; ++om)
          a[om] = *(const bhalf8*)(wbase + (om * 16 + l15) * 64);
#pragma unroll
        for (int p = 0; p < 4; ++p) {
          int tc = p * 16 + l15 + kw;  // input tile col (0..65)
          bb[p] = *(const bhalf8*)(lds + (r * 66 + tc) * 32 +
                                   ((l4 ^ ((tc >> 1) & 3)) << 3));
        }
#pragma unroll
        for (int om = 0; om < 4; ++om)
#pragma unroll
          for (int p = 0; p < 4; ++p)
            acc[om][p] = __builtin_amdgcn_mfma_f32_16x16x32_bf16(
                a[om], bb[p], acc[om][p], 0, 0, 0);
      }
    }
    __syncthreads();
  }

  // ---- epilogue: D[o = om*16 + l4*4 + j][px = p*16 + l15] + bias ----
  int h = h0 + wv;
#pragma unroll
  for (int om = 0; om < 4; ++om) {
#pragma unroll
    for (int j = 0; j < 4; ++j) {
      int o = om * 16 + l4 * 4 + j;
      float bo = bias[o];
      float* op = out + ((size_t)(n * 64 + o) * 224 + h) * 224 + w0;
#pragma unroll
      for (int p = 0; p < 4; ++p) {
        int wg = w0 + p * 16 + l15;
        if (wg < 224) op[p * 16 + l15] = acc[om][p][j] + bo;
      }
    }
  }
}

extern "C" void kernel_launch(void* const* d_in, const int* in_sizes, int n_in,
                              void* d_out, int out_size, void* d_ws,
                              size_t ws_size, hipStream_t stream) {
  const float* x = (const float*)d_in[0];
  const float* wloc = (const float*)d_in[1];
  const float* wL = (const float*)d_in[2];
  const float* bloc = (const float*)d_in[3];
  const float* bro = (const float*)d_in[4];
  const float* eps_w = (const float*)d_in[5];
  const float* eps_b = (const float*)d_in[6];
  float* outp = (float*)d_out;

  short* wt = (short*)d_ws;                        // 9*64*64 bf16 = 73728 B
  float* bias = (float*)((char*)d_ws + 73728);     // 64 f32

  prep_kernel<<<16, 256, 0, stream>>>(wloc, wL, eps_w, bloc, bro, eps_b, wt,
                                      bias);
  conv_kernel<<<3584, 512, 0, stream>>>(x, wt, bias, outp);
}